// Round 4
// baseline (1136.145 us; speedup 1.0000x reference)
//
#include <hip/hip_runtime.h>
#include <math.h>

// Problem constants
#define VV 32000   // vocab
#define SS 512     // states
#define BB 64      // batch
#define TT 256     // maxlen
#define NS 128     // column groups of 4 (512/4)
#define WSLOT (BB * SS)  // floats per w time-slot (32768)

// ---------------- setup kernels ----------------

// Column sums of exp(iw) over vocab rows. Block 0 also hosts one-time zero
// duties (out, colsum, flags) — consumers run in later kernels (stream order).
__global__ void k_colpart(const float* __restrict__ iw, float* __restrict__ psum,
                          float* __restrict__ out, float* __restrict__ colsum,
                          unsigned* __restrict__ flags) {
  const int blk = blockIdx.x;        // 250
  const int tid = threadIdx.x;       // 256
  if (blk == 0) {
    if (tid == 0) out[0] = 0.f;
    flags[tid] = 0u; flags[tid + 256] = 0u;       // 512 flags (L/H x 2 chains)
    colsum[tid] = 0.f; colsum[tid + 256] = 0.f;
  }
  const int cg = tid & 127;          // float4 column group
  const int rh = tid >> 7;           // row half
  const int r0 = blk * 128 + rh * 64;
  const float4* iw4 = (const float4*)iw;   // [32000][128] float4
  float4 s = make_float4(0.f, 0.f, 0.f, 0.f);
  #pragma unroll 4
  for (int r = 0; r < 64; ++r) {
    float4 x = iw4[(size_t)(r0 + r) * 128 + cg];
    s.x += __expf(x.x); s.y += __expf(x.y); s.z += __expf(x.z); s.w += __expf(x.w);
  }
  ((float4*)psum)[(size_t)(blk * 2 + rh) * 128 + cg] = s;
}

// 25 blocks x 512 thr: block p sums partial rows [20p, 20p+20) -> atomicAdd.
__global__ void k_colreduce(const float* __restrict__ psum, float* __restrict__ colsum) {
  const int c = threadIdx.x;         // 512
  const int p0 = blockIdx.x * 20;
  float s = 0.f;
  #pragma unroll 5
  for (int p = 0; p < 20; ++p) s += psum[(size_t)(p0 + p) * SS + c];
  atomicAdd(&colsum[c], s);
}

// P[i][j] = softmax(transition[i,:])[j] (row-major), q0vec[i] = sum_j P[i,j]*sb[j].
// softmax(begin) is recomputed locally per block (kills the k_begin kernel):
// sb[cc*64+lane] = bx[cc]*binv matches the P-column indexing exactly.
__global__ void k_transP(const float* __restrict__ trans, const float* __restrict__ begin,
                         float* __restrict__ P, float* __restrict__ q0vec) {
  const int i = blockIdx.x;     // 512 rows
  const int lane = threadIdx.x; // 64
  // local softmax(begin)
  float bx[8];
  float bm = -1e30f;
  #pragma unroll
  for (int cc = 0; cc < 8; ++cc) { bx[cc] = begin[cc * 64 + lane]; bm = fmaxf(bm, bx[cc]); }
  #pragma unroll
  for (int o = 32; o; o >>= 1) bm = fmaxf(bm, __shfl_xor(bm, o));
  float bs = 0.f;
  #pragma unroll
  for (int cc = 0; cc < 8; ++cc) { bx[cc] = __expf(bx[cc] - bm); bs += bx[cc]; }
  #pragma unroll
  for (int o = 32; o; o >>= 1) bs += __shfl_xor(bs, o);
  const float binv = 1.f / bs;

  const float* rp = trans + (size_t)i * SS;
  float xs[8];
  float m = -1e30f;
  #pragma unroll
  for (int cc = 0; cc < 8; ++cc) { xs[cc] = rp[cc * 64 + lane]; m = fmaxf(m, xs[cc]); }
  #pragma unroll
  for (int o = 32; o; o >>= 1) m = fmaxf(m, __shfl_xor(m, o));
  float s = 0.f;
  #pragma unroll
  for (int cc = 0; cc < 8; ++cc) s += __expf(xs[cc] - m);
  #pragma unroll
  for (int o = 32; o; o >>= 1) s += __shfl_xor(s, o);
  const float lse = m + __logf(s);
  float qa = 0.f;
  #pragma unroll
  for (int cc = 0; cc < 8; ++cc) {
    float p = __expf(xs[cc] - lse);
    P[(size_t)i * SS + cc * 64 + lane] = p;
    qa += p * (bx[cc] * binv);
  }
  #pragma unroll
  for (int o = 32; o; o >>= 1) qa += __shfl_xor(qa, o);
  if (lane == 0) q0vec[i] = qa;
}

// ---------------- persistent superstep kernel ----------------
// 256 blocks x 256 thr, cooperative. chain c = blk&1, col group g = blk>>1.
// Wave h = j-quarter. w ring WRITE-ONCE (slot = timestep): no stale-L2 hazard.
//
// Per-wave dataflow sync: wave h only consumes w produced by blocks
// [32h, 32h+32) of its chain, so it polls exactly those 32 flags and starts
// its GEMM quarter immediately (no global barrier, no max-of-128 skew).
// Producer split: h0 writes w states .x/.y (8B atomic) + flagL, h1 writes
// .z/.w + flagH, h2 writes dotpart. Each producer wave does vmcnt(0) on its
// single 8B store before its flag store -> flag visibility implies data at L3.
// One __syncthreads per iteration via double-buffered red[].
__global__ __launch_bounds__(256) void k_persist(
    const float* __restrict__ P, const float* __restrict__ q0vec,
    const float* __restrict__ iw, const float* __restrict__ colsum,
    const int* __restrict__ sent, float* __restrict__ wring,
    float* __restrict__ dotpart, unsigned* __restrict__ flags) {
  const int c = blockIdx.x & 1;
  const int g = blockIdx.x >> 1;       // 0..127
  const int lane = threadIdx.x & 63;   // batch b
  const int h = __builtin_amdgcn_readfirstlane(threadIdx.x >> 6); // j-quarter
  const int i0 = g << 2;
  const int kmax = c ? 127 : 128;
  unsigned* const flagL = flags + (c << 7);        // [c][g]
  unsigned* const flagH = flags + 256 + (c << 7);  // [c][g]
  const int gp = (h << 5) + (lane & 31);           // producer block for my quarter

  // colLSE computed locally (kills the k_lse kernel)
  float4 cl;
  cl.x = __logf(colsum[i0 + 0]); cl.y = __logf(colsum[i0 + 1]);
  cl.z = __logf(colsum[i0 + 2]); cl.w = __logf(colsum[i0 + 3]);

  const float4* const P0 = (const float4*)(P + (size_t)(i0 + 0) * SS) + h * 32;
  const float4* const P1 = (const float4*)(P + (size_t)(i0 + 1) * SS) + h * 32;
  const float4* const P2 = (const float4*)(P + (size_t)(i0 + 2) * SS) + h * 32;
  const float4* const P3 = (const float4*)(P + (size_t)(i0 + 3) * SS) + h * 32;

  __shared__ float4 red[2][4][64];

  for (int k = 0; k <= kmax; ++k) {
    const int rb = k & 1;
    const int t0 = 2 * k;
    const int tw = t0 + c;
    const int td = tw - 1;
    const bool doW = (h <= 1) && (tw <= 254);
    const bool doD = (h == 2) && (td >= 0);

    // Issue the scattered iw gathers early: their L2/L3 latency hides under
    // the flag poll + GEMM.
    float4 ivW = make_float4(0.f, 0.f, 0.f, 0.f);
    float4 ivD = make_float4(0.f, 0.f, 0.f, 0.f);
    if (doW) {
      const int row = sent[lane * TT + tw];
      ivW = *(const float4*)(iw + (size_t)row * SS + i0);
    }
    if (doD) {
      const int row = sent[lane * TT + td];
      ivD = *(const float4*)(iw + (size_t)row * SS + i0);
    }

    if (k > 0) {
      const unsigned tgt = (unsigned)k;
      for (;;) {
        const unsigned va = __hip_atomic_load(flagL + gp, __ATOMIC_RELAXED,
                                              __HIP_MEMORY_SCOPE_AGENT);
        const unsigned vb = __hip_atomic_load(flagH + gp, __ATOMIC_RELAXED,
                                              __HIP_MEMORY_SCOPE_AGENT);
        if (__all((va >= tgt) && (vb >= tgt))) break;
      }
      asm volatile("" ::: "memory");  // keep w loads below the poll
    }

    float a0 = 0.f, a1 = 0.f, a2 = 0.f, a3 = 0.f;
    if (t0 == 0) {
      if (h == 0) {
        a0 = q0vec[i0 + 0]; a1 = q0vec[i0 + 1];
        a2 = q0vec[i0 + 2]; a3 = q0vec[i0 + 3];
      }
    } else {
      // Full-depth prefetch: all 32 w float4 loads in flight at once,
      // then the FMA stream against L2-resident P.
      const float4* wv = (const float4*)(wring + (size_t)(tw - 2) * WSLOT)
                         + (size_t)h * 32 * 64;
      float4 wr[32];
      #pragma unroll
      for (int u = 0; u < 32; ++u) wr[u] = wv[u * 64 + lane];
      #pragma unroll
      for (int u = 0; u < 32; ++u) {
        const float4 p0 = P0[u];
        const float4 p1 = P1[u];
        const float4 p2 = P2[u];
        const float4 p3 = P3[u];
        a0 += wr[u].x * p0.x + wr[u].y * p0.y + wr[u].z * p0.z + wr[u].w * p0.w;
        a1 += wr[u].x * p1.x + wr[u].y * p1.y + wr[u].z * p1.z + wr[u].w * p1.w;
        a2 += wr[u].x * p2.x + wr[u].y * p2.y + wr[u].z * p2.z + wr[u].w * p2.w;
        a3 += wr[u].x * p3.x + wr[u].y * p3.y + wr[u].z * p3.z + wr[u].w * p3.w;
      }
    }

    red[rb][h][lane] = make_float4(a0, a1, a2, a3);
    __syncthreads();

    if (doW) {
      const float4 r0 = red[rb][0][lane], r1 = red[rb][1][lane];
      const float4 r2 = red[rb][2][lane], r3 = red[rb][3][lane];
      unsigned long long* wd = (unsigned long long*)
          ((float4*)(wring + (size_t)tw * WSLOT) + (g * 64 + lane));
      if (h == 0) {
        const float s0 = (r0.x + r1.x) + (r2.x + r3.x);
        const float s1 = (r0.y + r1.y) + (r2.y + r3.y);
        float w0 = s0 * __expf(ivW.x - cl.x);
        float w1 = s1 * __expf(ivW.y - cl.y);
        float c0 = w0, c1 = w1;
        #pragma unroll
        for (int o = 32; o; o >>= 1) { c0 += __shfl_xor(c0, o); c1 += __shfl_xor(c1, o); }
        union { float2 f; unsigned long long u; } lo;
        lo.f = make_float2(w0 / c0, w1 / c1);
        __hip_atomic_store(wd, lo.u, __ATOMIC_RELAXED, __HIP_MEMORY_SCOPE_AGENT);
        asm volatile("s_waitcnt vmcnt(0)" ::: "memory");  // w-lo acked at L3
        if (lane == 0)
          __hip_atomic_store(&flagL[g], (unsigned)(k + 1), __ATOMIC_RELAXED,
                             __HIP_MEMORY_SCOPE_AGENT);
      } else {
        const float s2 = (r0.z + r1.z) + (r2.z + r3.z);
        const float s3 = (r0.w + r1.w) + (r2.w + r3.w);
        float w2 = s2 * __expf(ivW.z - cl.z);
        float w3 = s3 * __expf(ivW.w - cl.w);
        float c2 = w2, c3 = w3;
        #pragma unroll
        for (int o = 32; o; o >>= 1) { c2 += __shfl_xor(c2, o); c3 += __shfl_xor(c3, o); }
        union { float2 f; unsigned long long u; } hi;
        hi.f = make_float2(w2 / c2, w3 / c3);
        __hip_atomic_store(wd + 1, hi.u, __ATOMIC_RELAXED, __HIP_MEMORY_SCOPE_AGENT);
        asm volatile("s_waitcnt vmcnt(0)" ::: "memory");  // w-hi acked at L3
        if (lane == 0)
          __hip_atomic_store(&flagH[g], (unsigned)(k + 1), __ATOMIC_RELAXED,
                             __HIP_MEMORY_SCOPE_AGENT);
      }
    } else if (doD) {
      const float4 r0 = red[rb][0][lane], r1 = red[rb][1][lane];
      const float4 r2 = red[rb][2][lane], r3 = red[rb][3][lane];
      const float s0 = (r0.x + r1.x) + (r2.x + r3.x);
      const float s1 = (r0.y + r1.y) + (r2.y + r3.y);
      const float s2 = (r0.z + r1.z) + (r2.z + r3.z);
      const float s3 = (r0.w + r1.w) + (r2.w + r3.w);
      const float dp = s0 * __expf(ivD.x - cl.x)
                     + s1 * __expf(ivD.y - cl.y)
                     + s2 * __expf(ivD.z - cl.z)
                     + s3 * __expf(ivD.w - cl.w);
      dotpart[((size_t)td * NS + g) * BB + lane] = dp;  // plain store: k_final is a
                                                        // separate kernel (boundary flush)
    }
  }
}

// ---------------- final reduction ----------------
__global__ void k_final(const float* __restrict__ dotpart, const float* __restrict__ masks,
                        float* __restrict__ out) {
  const int t = blockIdx.x;    // 256
  const int tid = threadIdx.x; // 256
  const int b = tid & 63, g = tid >> 6;
  float sum = 0.f;
  for (int s = g; s < NS; s += 4) sum += dotpart[((size_t)t * NS + s) * BB + b];
  __shared__ float red[4][64];
  red[g][b] = sum;
  __syncthreads();
  if (g == 0) {
    float tot = (red[0][b] + red[1][b]) + (red[2][b] + red[3][b]);
    float v = __logf(tot) * masks[b * TT + t];
    #pragma unroll
    for (int o = 32; o; o >>= 1) v += __shfl_xor(v, o);
    if (b == 0) atomicAdd(out, v);
  }
}

extern "C" void kernel_launch(void* const* d_in, const int* in_sizes, int n_in,
                              void* d_out, int out_size, void* d_ws, size_t ws_size,
                              hipStream_t stream) {
  const int* sent = (const int*)d_in[0];     // [64][256] int32
  const float* masks = (const float*)d_in[1];// [64][256]
  const float* iw = (const float*)d_in[2];   // [32000][512]
  const float* trans = (const float*)d_in[3];// [512][512]
  const float* begin = (const float*)d_in[4];// [512]
  float* out = (float*)d_out;
  float* ws = (float*)d_ws;

  // workspace carve (floats)
  float* P = ws;                            // 262144
  float* psum = P + 262144;                 // 500*512 = 256000
  float* colsum = psum + 256000;            // 512
  float* q0vec = colsum + 512;              // 512
  float* dotpart = q0vec + 512;             // 256*128*64 = 2097152
  unsigned* flags = (unsigned*)(dotpart + 2097152); // 512 used, 512 reserved
  float* wring = (float*)flags + 512;       // 255 * 32768 = 8355840 (~33.4 MB)
  // total ~44 MB

  k_colpart<<<250, 256, 0, stream>>>(iw, psum, out, colsum, flags);
  k_colreduce<<<25, 512, 0, stream>>>(psum, colsum);
  k_transP<<<512, 64, 0, stream>>>(trans, begin, P, q0vec);

  {
    const float* Pp = P;
    const float* q0p = q0vec;
    const float* iwp = iw;
    const float* csp = colsum;
    const int* sentp = sent;
    float* wrp = wring;
    float* dpp = dotpart;
    unsigned* fp = flags;
    void* args[] = {&Pp, &q0p, &iwp, &csp, &sentp, &wrp, &dpp, &fp};
    (void)hipLaunchCooperativeKernel((const void*)k_persist, dim3(256), dim3(256),
                                     args, 0, stream);
  }

  k_final<<<TT, 256, 0, stream>>>(dotpart, masks, out);
}

// Round 5
// 1123.169 us; speedup vs baseline: 1.0116x; 1.0116x over previous
//
#include <hip/hip_runtime.h>
#include <math.h>

// Problem constants
#define VV 32000   // vocab
#define SS 512     // states
#define BB 64      // batch
#define TT 256     // maxlen
#define NS 128     // column groups of 4 (512/4)
#define WSLOT (BB * SS)  // floats per w time-slot (32768)

// ---------------- setup kernels ----------------

// Column sums of exp(iw) over vocab rows. Block 0 also hosts one-time zero
// duties (out, colsum, flags) — consumers run in later kernels (stream order).
__global__ void k_colpart(const float* __restrict__ iw, float* __restrict__ psum,
                          float* __restrict__ out, float* __restrict__ colsum,
                          unsigned* __restrict__ flags) {
  const int blk = blockIdx.x;        // 250
  const int tid = threadIdx.x;       // 256
  if (blk == 0) {
    if (tid == 0) out[0] = 0.f;
    flags[tid] = 0u;                               // 256 flags (2 chains x 128)
    colsum[tid] = 0.f; colsum[tid + 256] = 0.f;
  }
  const int cg = tid & 127;          // float4 column group
  const int rh = tid >> 7;           // row half
  const int r0 = blk * 128 + rh * 64;
  const float4* iw4 = (const float4*)iw;   // [32000][128] float4
  float4 s = make_float4(0.f, 0.f, 0.f, 0.f);
  #pragma unroll 4
  for (int r = 0; r < 64; ++r) {
    float4 x = iw4[(size_t)(r0 + r) * 128 + cg];
    s.x += __expf(x.x); s.y += __expf(x.y); s.z += __expf(x.z); s.w += __expf(x.w);
  }
  ((float4*)psum)[(size_t)(blk * 2 + rh) * 128 + cg] = s;
}

// 25 blocks x 512 thr: block p sums partial rows [20p, 20p+20) -> atomicAdd.
__global__ void k_colreduce(const float* __restrict__ psum, float* __restrict__ colsum) {
  const int c = threadIdx.x;         // 512
  const int p0 = blockIdx.x * 20;
  float s = 0.f;
  #pragma unroll 5
  for (int p = 0; p < 20; ++p) s += psum[(size_t)(p0 + p) * SS + c];
  atomicAdd(&colsum[c], s);
}

// P[i][j] = softmax(transition[i,:])[j] (row-major), q0vec[i] = sum_j P[i,j]*sb[j].
// softmax(begin) recomputed locally per block (no separate k_begin kernel).
__global__ void k_transP(const float* __restrict__ trans, const float* __restrict__ begin,
                         float* __restrict__ P, float* __restrict__ q0vec) {
  const int i = blockIdx.x;     // 512 rows
  const int lane = threadIdx.x; // 64
  // local softmax(begin)
  float bx[8];
  float bm = -1e30f;
  #pragma unroll
  for (int cc = 0; cc < 8; ++cc) { bx[cc] = begin[cc * 64 + lane]; bm = fmaxf(bm, bx[cc]); }
  #pragma unroll
  for (int o = 32; o; o >>= 1) bm = fmaxf(bm, __shfl_xor(bm, o));
  float bs = 0.f;
  #pragma unroll
  for (int cc = 0; cc < 8; ++cc) { bx[cc] = __expf(bx[cc] - bm); bs += bx[cc]; }
  #pragma unroll
  for (int o = 32; o; o >>= 1) bs += __shfl_xor(bs, o);
  const float binv = 1.f / bs;

  const float* rp = trans + (size_t)i * SS;
  float xs[8];
  float m = -1e30f;
  #pragma unroll
  for (int cc = 0; cc < 8; ++cc) { xs[cc] = rp[cc * 64 + lane]; m = fmaxf(m, xs[cc]); }
  #pragma unroll
  for (int o = 32; o; o >>= 1) m = fmaxf(m, __shfl_xor(m, o));
  float s = 0.f;
  #pragma unroll
  for (int cc = 0; cc < 8; ++cc) s += __expf(xs[cc] - m);
  #pragma unroll
  for (int o = 32; o; o >>= 1) s += __shfl_xor(s, o);
  const float lse = m + __logf(s);
  float qa = 0.f;
  #pragma unroll
  for (int cc = 0; cc < 8; ++cc) {
    float p = __expf(xs[cc] - lse);
    P[(size_t)i * SS + cc * 64 + lane] = p;
    qa += p * (bx[cc] * binv);
  }
  #pragma unroll
  for (int o = 32; o; o >>= 1) qa += __shfl_xor(qa, o);
  if (lane == 0) q0vec[i] = qa;
}

// ---------------- persistent superstep kernel ----------------
// 256 blocks x 256 thr, cooperative. chain c = blk&1, col group g = blk>>1.
// Wave h = j-quarter. w ring WRITE-ONCE (slot = timestep): no stale-L2 hazard.
//
// Sync design (R5): single flag per (chain, block). Producer wave h0 writes
// all 4 w states (two 8B agent-scope write-through stores), vmcnt(0), then
// the flag — flag visibility implies w at L3. Consumption is PER-WAVE
// dataflow: wave h needs only w states [128h,128h+128), produced by blocks
// [32h,32h+32) of its chain, so it polls exactly those 32 flags (one load +
// __all, s_sleep(1)-throttled) and self-releases into its GEMM. No global
// release barrier -> skew is max-of-32, not max-of-128. One __syncthreads
// per iteration (red exchange, double-buffered; the k+1 barrier orders
// iter-k reads before iter-k+2 writes).
__global__ __launch_bounds__(256) void k_persist(
    const float* __restrict__ P, const float* __restrict__ q0vec,
    const float* __restrict__ iw, const float* __restrict__ colsum,
    const int* __restrict__ sent, float* __restrict__ wring,
    float* __restrict__ dotpart, unsigned* __restrict__ flags) {
  const int c = blockIdx.x & 1;
  const int g = blockIdx.x >> 1;       // 0..127
  const int lane = threadIdx.x & 63;   // batch b
  const int h = __builtin_amdgcn_readfirstlane(threadIdx.x >> 6); // j-quarter
  const int i0 = g << 2;
  const int kmax = c ? 127 : 128;
  unsigned* const chflags = flags + (c << 7);      // [c][g]
  const int gp = (h << 5) + (lane & 31);           // my quarter's producer blocks

  // colLSE computed locally
  float4 cl;
  cl.x = __logf(colsum[i0 + 0]); cl.y = __logf(colsum[i0 + 1]);
  cl.z = __logf(colsum[i0 + 2]); cl.w = __logf(colsum[i0 + 3]);

  const float4* const P0 = (const float4*)(P + (size_t)(i0 + 0) * SS) + h * 32;
  const float4* const P1 = (const float4*)(P + (size_t)(i0 + 1) * SS) + h * 32;
  const float4* const P2 = (const float4*)(P + (size_t)(i0 + 2) * SS) + h * 32;
  const float4* const P3 = (const float4*)(P + (size_t)(i0 + 3) * SS) + h * 32;

  __shared__ float4 red[2][4][64];

  for (int k = 0; k <= kmax; ++k) {
    const int rb = k & 1;
    const int t0 = 2 * k;
    const int tw = t0 + c;
    const int td = tw - 1;
    const bool doW = (h == 0) && (tw <= 254);
    const bool doD = (h == 1) && (td >= 0);

    // Issue the scattered iw gathers early: their L2/L3 latency hides under
    // the flag poll + GEMM.
    float4 ivW = make_float4(0.f, 0.f, 0.f, 0.f);
    float4 ivD = make_float4(0.f, 0.f, 0.f, 0.f);
    if (doW) {
      const int row = sent[lane * TT + tw];
      ivW = *(const float4*)(iw + (size_t)row * SS + i0);
    }
    if (doD) {
      const int row = sent[lane * TT + td];
      ivD = *(const float4*)(iw + (size_t)row * SS + i0);
    }

    if (k > 0) {
      const unsigned tgt = (unsigned)k;
      for (;;) {
        const unsigned v = __hip_atomic_load(chflags + gp, __ATOMIC_RELAXED,
                                             __HIP_MEMORY_SCOPE_AGENT);
        if (__all(v >= tgt)) break;
        __builtin_amdgcn_s_sleep(1);
      }
      asm volatile("" ::: "memory");  // keep w loads below the poll
    }

    float a0 = 0.f, a1 = 0.f, a2 = 0.f, a3 = 0.f;
    if (t0 == 0) {
      if (h == 0) {
        a0 = q0vec[i0 + 0]; a1 = q0vec[i0 + 1];
        a2 = q0vec[i0 + 2]; a3 = q0vec[i0 + 3];
      }
    } else {
      // Full-depth prefetch: all 32 w float4 loads in flight at once,
      // then the FMA stream against L2-resident P.
      const float4* wv = (const float4*)(wring + (size_t)(tw - 2) * WSLOT)
                         + (size_t)h * 32 * 64;
      float4 wr[32];
      #pragma unroll
      for (int u = 0; u < 32; ++u) wr[u] = wv[u * 64 + lane];
      #pragma unroll
      for (int u = 0; u < 32; ++u) {
        const float4 p0 = P0[u];
        const float4 p1 = P1[u];
        const float4 p2 = P2[u];
        const float4 p3 = P3[u];
        a0 += wr[u].x * p0.x + wr[u].y * p0.y + wr[u].z * p0.z + wr[u].w * p0.w;
        a1 += wr[u].x * p1.x + wr[u].y * p1.y + wr[u].z * p1.z + wr[u].w * p1.w;
        a2 += wr[u].x * p2.x + wr[u].y * p2.y + wr[u].z * p2.z + wr[u].w * p2.w;
        a3 += wr[u].x * p3.x + wr[u].y * p3.y + wr[u].z * p3.z + wr[u].w * p3.w;
      }
    }

    red[rb][h][lane] = make_float4(a0, a1, a2, a3);
    __syncthreads();

    if (doW) {
      const float4 r0 = red[rb][0][lane], r1 = red[rb][1][lane];
      const float4 r2 = red[rb][2][lane], r3 = red[rb][3][lane];
      const float s0 = (r0.x + r1.x) + (r2.x + r3.x);
      const float s1 = (r0.y + r1.y) + (r2.y + r3.y);
      const float s2 = (r0.z + r1.z) + (r2.z + r3.z);
      const float s3 = (r0.w + r1.w) + (r2.w + r3.w);
      float w0 = s0 * __expf(ivW.x - cl.x);
      float w1 = s1 * __expf(ivW.y - cl.y);
      float w2 = s2 * __expf(ivW.z - cl.z);
      float w3 = s3 * __expf(ivW.w - cl.w);
      float c0 = w0, c1 = w1, c2 = w2, c3 = w3;
      #pragma unroll
      for (int o = 32; o; o >>= 1) {
        c0 += __shfl_xor(c0, o);
        c1 += __shfl_xor(c1, o);
        c2 += __shfl_xor(c2, o);
        c3 += __shfl_xor(c3, o);
      }
      // write-through (agent) stores: data reaches L3 (coherence point)
      union { float2 f; unsigned long long u; } lo, hi;
      lo.f = make_float2(w0 / c0, w1 / c1);
      hi.f = make_float2(w2 / c2, w3 / c3);
      unsigned long long* wd = (unsigned long long*)
          ((float4*)(wring + (size_t)tw * WSLOT) + (g * 64 + lane));
      __hip_atomic_store(wd, lo.u, __ATOMIC_RELAXED, __HIP_MEMORY_SCOPE_AGENT);
      __hip_atomic_store(wd + 1, hi.u, __ATOMIC_RELAXED, __HIP_MEMORY_SCOPE_AGENT);
      asm volatile("s_waitcnt vmcnt(0)" ::: "memory");  // w acked at L3
      if (lane == 0)
        __hip_atomic_store(&chflags[g], (unsigned)(k + 1), __ATOMIC_RELAXED,
                           __HIP_MEMORY_SCOPE_AGENT);
    } else if (doD) {
      const float4 r0 = red[rb][0][lane], r1 = red[rb][1][lane];
      const float4 r2 = red[rb][2][lane], r3 = red[rb][3][lane];
      const float s0 = (r0.x + r1.x) + (r2.x + r3.x);
      const float s1 = (r0.y + r1.y) + (r2.y + r3.y);
      const float s2 = (r0.z + r1.z) + (r2.z + r3.z);
      const float s3 = (r0.w + r1.w) + (r2.w + r3.w);
      const float dp = s0 * __expf(ivD.x - cl.x)
                     + s1 * __expf(ivD.y - cl.y)
                     + s2 * __expf(ivD.z - cl.z)
                     + s3 * __expf(ivD.w - cl.w);
      dotpart[((size_t)td * NS + g) * BB + lane] = dp;  // plain store: k_final is a
                                                        // separate kernel (boundary flush)
    }
  }
}

// ---------------- final reduction ----------------
__global__ void k_final(const float* __restrict__ dotpart, const float* __restrict__ masks,
                        float* __restrict__ out) {
  const int t = blockIdx.x;    // 256
  const int tid = threadIdx.x; // 256
  const int b = tid & 63, g = tid >> 6;
  float sum = 0.f;
  for (int s = g; s < NS; s += 4) sum += dotpart[((size_t)t * NS + s) * BB + b];
  __shared__ float red[4][64];
  red[g][b] = sum;
  __syncthreads();
  if (g == 0) {
    float tot = (red[0][b] + red[1][b]) + (red[2][b] + red[3][b]);
    float v = __logf(tot) * masks[b * TT + t];
    #pragma unroll
    for (int o = 32; o; o >>= 1) v += __shfl_xor(v, o);
    if (b == 0) atomicAdd(out, v);
  }
}

extern "C" void kernel_launch(void* const* d_in, const int* in_sizes, int n_in,
                              void* d_out, int out_size, void* d_ws, size_t ws_size,
                              hipStream_t stream) {
  const int* sent = (const int*)d_in[0];     // [64][256] int32
  const float* masks = (const float*)d_in[1];// [64][256]
  const float* iw = (const float*)d_in[2];   // [32000][512]
  const float* trans = (const float*)d_in[3];// [512][512]
  const float* begin = (const float*)d_in[4];// [512]
  float* out = (float*)d_out;
  float* ws = (float*)d_ws;

  // workspace carve (floats)
  float* P = ws;                            // 262144
  float* psum = P + 262144;                 // 500*512 = 256000
  float* colsum = psum + 256000;            // 512
  float* q0vec = colsum + 512;              // 512
  float* dotpart = q0vec + 512;             // 256*128*64 = 2097152
  unsigned* flags = (unsigned*)(dotpart + 2097152); // 256 used, 512 reserved
  float* wring = (float*)flags + 512;       // 255 * 32768 = 8355840 (~33.4 MB)
  // total ~44 MB

  k_colpart<<<250, 256, 0, stream>>>(iw, psum, out, colsum, flags);
  k_colreduce<<<25, 512, 0, stream>>>(psum, colsum);
  k_transP<<<512, 64, 0, stream>>>(trans, begin, P, q0vec);

  {
    const float* Pp = P;
    const float* q0p = q0vec;
    const float* iwp = iw;
    const float* csp = colsum;
    const int* sentp = sent;
    float* wrp = wring;
    float* dpp = dotpart;
    unsigned* fp = flags;
    void* args[] = {&Pp, &q0p, &iwp, &csp, &sentp, &wrp, &dpp, &fp};
    (void)hipLaunchCooperativeKernel((const void*)k_persist, dim3(256), dim3(256),
                                     args, 0, stream);
  }

  k_final<<<TT, 256, 0, stream>>>(dotpart, masks, out);
}

// Round 6
// 1098.632 us; speedup vs baseline: 1.0341x; 1.0223x over previous
//
#include <hip/hip_runtime.h>
#include <math.h>

// Problem constants
#define VV 32000   // vocab
#define SS 512     // states
#define BB 64      // batch
#define TT 256     // maxlen
#define NS 128     // column groups of 4 (512/4)
#define WSLOT (BB * SS)  // floats per w time-slot (32768)

// ---------------- setup kernels ----------------

// Column sums of exp(iw) over vocab rows. Block 0 also hosts one-time zero
// duties (out, colsum, flags) — consumers run in later kernels (stream order).
__global__ void k_colpart(const float* __restrict__ iw, float* __restrict__ psum,
                          float* __restrict__ out, float* __restrict__ colsum,
                          unsigned* __restrict__ flags) {
  const int blk = blockIdx.x;        // 250
  const int tid = threadIdx.x;       // 256
  if (blk == 0) {
    if (tid == 0) out[0] = 0.f;
    flags[tid] = 0u;                               // 256 flags (2 chains x 128)
    colsum[tid] = 0.f; colsum[tid + 256] = 0.f;
  }
  const int cg = tid & 127;          // float4 column group
  const int rh = tid >> 7;           // row half
  const int r0 = blk * 128 + rh * 64;
  const float4* iw4 = (const float4*)iw;   // [32000][128] float4
  float4 s = make_float4(0.f, 0.f, 0.f, 0.f);
  #pragma unroll 4
  for (int r = 0; r < 64; ++r) {
    float4 x = iw4[(size_t)(r0 + r) * 128 + cg];
    s.x += __expf(x.x); s.y += __expf(x.y); s.z += __expf(x.z); s.w += __expf(x.w);
  }
  ((float4*)psum)[(size_t)(blk * 2 + rh) * 128 + cg] = s;
}

// 25 blocks x 512 thr: block p sums partial rows [20p, 20p+20) -> atomicAdd.
__global__ void k_colreduce(const float* __restrict__ psum, float* __restrict__ colsum) {
  const int c = threadIdx.x;         // 512
  const int p0 = blockIdx.x * 20;
  float s = 0.f;
  #pragma unroll 5
  for (int p = 0; p < 20; ++p) s += psum[(size_t)(p0 + p) * SS + c];
  atomicAdd(&colsum[c], s);
}

// P[i][j] = softmax(transition[i,:])[j] (row-major), q0vec[i] = sum_j P[i,j]*sb[j].
// softmax(begin) recomputed locally per block (no separate k_begin kernel).
__global__ void k_transP(const float* __restrict__ trans, const float* __restrict__ begin,
                         float* __restrict__ P, float* __restrict__ q0vec) {
  const int i = blockIdx.x;     // 512 rows
  const int lane = threadIdx.x; // 64
  // local softmax(begin)
  float bx[8];
  float bm = -1e30f;
  #pragma unroll
  for (int cc = 0; cc < 8; ++cc) { bx[cc] = begin[cc * 64 + lane]; bm = fmaxf(bm, bx[cc]); }
  #pragma unroll
  for (int o = 32; o; o >>= 1) bm = fmaxf(bm, __shfl_xor(bm, o));
  float bs = 0.f;
  #pragma unroll
  for (int cc = 0; cc < 8; ++cc) { bx[cc] = __expf(bx[cc] - bm); bs += bx[cc]; }
  #pragma unroll
  for (int o = 32; o; o >>= 1) bs += __shfl_xor(bs, o);
  const float binv = 1.f / bs;

  const float* rp = trans + (size_t)i * SS;
  float xs[8];
  float m = -1e30f;
  #pragma unroll
  for (int cc = 0; cc < 8; ++cc) { xs[cc] = rp[cc * 64 + lane]; m = fmaxf(m, xs[cc]); }
  #pragma unroll
  for (int o = 32; o; o >>= 1) m = fmaxf(m, __shfl_xor(m, o));
  float s = 0.f;
  #pragma unroll
  for (int cc = 0; cc < 8; ++cc) s += __expf(xs[cc] - m);
  #pragma unroll
  for (int o = 32; o; o >>= 1) s += __shfl_xor(s, o);
  const float lse = m + __logf(s);
  float qa = 0.f;
  #pragma unroll
  for (int cc = 0; cc < 8; ++cc) {
    float p = __expf(xs[cc] - lse);
    P[(size_t)i * SS + cc * 64 + lane] = p;
    qa += p * (bx[cc] * binv);
  }
  #pragma unroll
  for (int o = 32; o; o >>= 1) qa += __shfl_xor(qa, o);
  if (lane == 0) q0vec[i] = qa;
}

// ---------------- persistent superstep kernel ----------------
// 256 blocks x 256 thr, cooperative. chain c = blk&1, col group g = blk>>1.
// Wave h = j-quarter. w ring WRITE-ONCE (slot = timestep): no stale-L2 hazard.
//
// R6 schedule, per iteration k:
//   [bar1]  -> iw gathers issued -> GEMM (w[tw-2] x P quarter) -> red store
//   [bar2]  -> tail duties, overlapped across waves:
//       h0 (producer): sums from red, shfl-normalize, w stores (sc1
//           write-through), vmcnt(0) ack, flag := k+1.
//       h1 (scout): poll ALL OTHER blocks' flags >= k+1 (skip own flag —
//           bar1 already orders own ack before any consumer load). Runs
//           CONCURRENT with h0's epilogue -> detect latency is hidden.
//       h2: dotpart store. h3: idle.
// One scout per block (R3's proven poll discipline — R4/R5 showed 4
// free-running pollers congest the flag lines and every L3 hop).
__global__ __launch_bounds__(256) void k_persist(
    const float* __restrict__ P, const float* __restrict__ q0vec,
    const float* __restrict__ iw, const float* __restrict__ colsum,
    const int* __restrict__ sent, float* __restrict__ wring,
    float* __restrict__ dotpart, unsigned* __restrict__ flags) {
  const int c = blockIdx.x & 1;
  const int g = blockIdx.x >> 1;       // 0..127
  const int lane = threadIdx.x & 63;   // batch b
  const int h = __builtin_amdgcn_readfirstlane(threadIdx.x >> 6); // j-quarter
  const int i0 = g << 2;
  const int kmax = c ? 127 : 128;
  unsigned* const chflags = flags + (c << 7);      // [c][g]

  // colLSE computed locally
  float4 cl;
  cl.x = __logf(colsum[i0 + 0]); cl.y = __logf(colsum[i0 + 1]);
  cl.z = __logf(colsum[i0 + 2]); cl.w = __logf(colsum[i0 + 3]);

  const float4* const P0 = (const float4*)(P + (size_t)(i0 + 0) * SS) + h * 32;
  const float4* const P1 = (const float4*)(P + (size_t)(i0 + 1) * SS) + h * 32;
  const float4* const P2 = (const float4*)(P + (size_t)(i0 + 2) * SS) + h * 32;
  const float4* const P3 = (const float4*)(P + (size_t)(i0 + 3) * SS) + h * 32;

  __shared__ float4 red[4][64];

  for (int k = 0; k <= kmax; ++k) {
    const int t0 = 2 * k;
    const int tw = t0 + c;
    const int td = tw - 1;
    const bool doW = (h == 0) && (tw <= 254);
    const bool doD = (h == 2) && (td >= 0);

    if (k > 0) __syncthreads();  // bar1: scout detect + producer epilogue done

    // iw gathers for this iteration's tail duties — issued before the GEMM
    // so their L2/L3 latency hides under it.
    float4 ivW = make_float4(0.f, 0.f, 0.f, 0.f);
    float4 ivD = make_float4(0.f, 0.f, 0.f, 0.f);
    if (doW) {
      const int row = sent[lane * TT + tw];
      ivW = *(const float4*)(iw + (size_t)row * SS + i0);
    }
    if (doD) {
      const int row = sent[lane * TT + td];
      ivD = *(const float4*)(iw + (size_t)row * SS + i0);
    }

    float a0 = 0.f, a1 = 0.f, a2 = 0.f, a3 = 0.f;
    if (t0 == 0) {
      if (h == 0) {
        a0 = q0vec[i0 + 0]; a1 = q0vec[i0 + 1];
        a2 = q0vec[i0 + 2]; a3 = q0vec[i0 + 3];
      }
    } else {
      // Full-depth prefetch: all 32 w float4 loads in flight at once,
      // then the FMA stream against L1/L2-resident P.
      const float4* wv = (const float4*)(wring + (size_t)(tw - 2) * WSLOT)
                         + (size_t)h * 32 * 64;
      float4 wr[32];
      #pragma unroll
      for (int u = 0; u < 32; ++u) wr[u] = wv[u * 64 + lane];
      #pragma unroll
      for (int u = 0; u < 32; ++u) {
        const float4 p0 = P0[u];
        const float4 p1 = P1[u];
        const float4 p2 = P2[u];
        const float4 p3 = P3[u];
        a0 += wr[u].x * p0.x + wr[u].y * p0.y + wr[u].z * p0.z + wr[u].w * p0.w;
        a1 += wr[u].x * p1.x + wr[u].y * p1.y + wr[u].z * p1.z + wr[u].w * p1.w;
        a2 += wr[u].x * p2.x + wr[u].y * p2.y + wr[u].z * p2.z + wr[u].w * p2.w;
        a3 += wr[u].x * p3.x + wr[u].y * p3.y + wr[u].z * p3.z + wr[u].w * p3.w;
      }
    }

    red[h][lane] = make_float4(a0, a1, a2, a3);
    __syncthreads();  // bar2

    if (doW) {
      // ---- producer (h0) ----
      const float4 r0 = red[0][lane], r1 = red[1][lane];
      const float4 r2 = red[2][lane], r3 = red[3][lane];
      const float s0 = (r0.x + r1.x) + (r2.x + r3.x);
      const float s1 = (r0.y + r1.y) + (r2.y + r3.y);
      const float s2 = (r0.z + r1.z) + (r2.z + r3.z);
      const float s3 = (r0.w + r1.w) + (r2.w + r3.w);
      float w0 = s0 * __expf(ivW.x - cl.x);
      float w1 = s1 * __expf(ivW.y - cl.y);
      float w2 = s2 * __expf(ivW.z - cl.z);
      float w3 = s3 * __expf(ivW.w - cl.w);
      float c0 = w0, c1 = w1, c2 = w2, c3 = w3;
      #pragma unroll
      for (int o = 32; o; o >>= 1) {
        c0 += __shfl_xor(c0, o);
        c1 += __shfl_xor(c1, o);
        c2 += __shfl_xor(c2, o);
        c3 += __shfl_xor(c3, o);
      }
      // write-through (agent) stores: data reaches L3 (coherence point)
      union { float2 f; unsigned long long u; } lo, hi;
      lo.f = make_float2(w0 / c0, w1 / c1);
      hi.f = make_float2(w2 / c2, w3 / c3);
      unsigned long long* wd = (unsigned long long*)
          ((float4*)(wring + (size_t)tw * WSLOT) + (g * 64 + lane));
      __hip_atomic_store(wd, lo.u, __ATOMIC_RELAXED, __HIP_MEMORY_SCOPE_AGENT);
      __hip_atomic_store(wd + 1, hi.u, __ATOMIC_RELAXED, __HIP_MEMORY_SCOPE_AGENT);
      asm volatile("s_waitcnt vmcnt(0)" ::: "memory");  // w acked at L3
      if (lane == 0)
        __hip_atomic_store(&chflags[g], (unsigned)(k + 1), __ATOMIC_RELAXED,
                           __HIP_MEMORY_SCOPE_AGENT);
    } else if (doD) {
      // ---- dotpart (h2) ----
      const float4 r0 = red[0][lane], r1 = red[1][lane];
      const float4 r2 = red[2][lane], r3 = red[3][lane];
      const float s0 = (r0.x + r1.x) + (r2.x + r3.x);
      const float s1 = (r0.y + r1.y) + (r2.y + r3.y);
      const float s2 = (r0.z + r1.z) + (r2.z + r3.z);
      const float s3 = (r0.w + r1.w) + (r2.w + r3.w);
      const float dp = s0 * __expf(ivD.x - cl.x)
                     + s1 * __expf(ivD.y - cl.y)
                     + s2 * __expf(ivD.z - cl.z)
                     + s3 * __expf(ivD.w - cl.w);
      dotpart[((size_t)td * NS + g) * BB + lane] = dp;  // plain store: k_final is a
                                                        // separate kernel (boundary flush)
    } else if (h == 1 && k < kmax) {
      // ---- scout (h1): poll for NEXT iteration, overlapped with h0's
      // epilogue. Skip own block's flag (bar1 orders own ack anyway).
      const unsigned tgt = (unsigned)(k + 1);
      for (;;) {
        const unsigned va = __hip_atomic_load(chflags + lane, __ATOMIC_RELAXED,
                                              __HIP_MEMORY_SCOPE_AGENT);
        const unsigned vb = __hip_atomic_load(chflags + 64 + lane, __ATOMIC_RELAXED,
                                              __HIP_MEMORY_SCOPE_AGENT);
        const bool ok = ((va >= tgt) || (lane == g)) &&
                        ((vb >= tgt) || ((lane + 64) == g));
        if (__all(ok)) break;
      }
    }
  }
}

// ---------------- final reduction ----------------
__global__ void k_final(const float* __restrict__ dotpart, const float* __restrict__ masks,
                        float* __restrict__ out) {
  const int t = blockIdx.x;    // 256
  const int tid = threadIdx.x; // 256
  const int b = tid & 63, g = tid >> 6;
  float sum = 0.f;
  for (int s = g; s < NS; s += 4) sum += dotpart[((size_t)t * NS + s) * BB + b];
  __shared__ float red[4][64];
  red[g][b] = sum;
  __syncthreads();
  if (g == 0) {
    float tot = (red[0][b] + red[1][b]) + (red[2][b] + red[3][b]);
    float v = __logf(tot) * masks[b * TT + t];
    #pragma unroll
    for (int o = 32; o; o >>= 1) v += __shfl_xor(v, o);
    if (b == 0) atomicAdd(out, v);
  }
}

extern "C" void kernel_launch(void* const* d_in, const int* in_sizes, int n_in,
                              void* d_out, int out_size, void* d_ws, size_t ws_size,
                              hipStream_t stream) {
  const int* sent = (const int*)d_in[0];     // [64][256] int32
  const float* masks = (const float*)d_in[1];// [64][256]
  const float* iw = (const float*)d_in[2];   // [32000][512]
  const float* trans = (const float*)d_in[3];// [512][512]
  const float* begin = (const float*)d_in[4];// [512]
  float* out = (float*)d_out;
  float* ws = (float*)d_ws;

  // workspace carve (floats)
  float* P = ws;                            // 262144
  float* psum = P + 262144;                 // 500*512 = 256000
  float* colsum = psum + 256000;            // 512
  float* q0vec = colsum + 512;              // 512
  float* dotpart = q0vec + 512;             // 256*128*64 = 2097152
  unsigned* flags = (unsigned*)(dotpart + 2097152); // 256 used, 512 reserved
  float* wring = (float*)flags + 512;       // 255 * 32768 = 8355840 (~33.4 MB)
  // total ~44 MB

  k_colpart<<<250, 256, 0, stream>>>(iw, psum, out, colsum, flags);
  k_colreduce<<<25, 512, 0, stream>>>(psum, colsum);
  k_transP<<<512, 64, 0, stream>>>(trans, begin, P, q0vec);

  {
    const float* Pp = P;
    const float* q0p = q0vec;
    const float* iwp = iw;
    const float* csp = colsum;
    const int* sentp = sent;
    float* wrp = wring;
    float* dpp = dotpart;
    unsigned* fp = flags;
    void* args[] = {&Pp, &q0p, &iwp, &csp, &sentp, &wrp, &dpp, &fp};
    (void)hipLaunchCooperativeKernel((const void*)k_persist, dim3(256), dim3(256),
                                     args, 0, stream);
  }

  k_final<<<TT, 256, 0, stream>>>(dotpart, masks, out);
}

// Round 7
// 794.212 us; speedup vs baseline: 1.4305x; 1.3833x over previous
//
#include <hip/hip_runtime.h>
#include <math.h>

// Problem constants
#define VV 32000   // vocab
#define SS 512     // states
#define BB 64      // batch
#define TT 256     // maxlen
#define NS 128     // column groups of 4 (512/4)
#define WSLOT (BB * SS)  // floats per w time-slot (32768)

// ---------------- setup kernels ----------------

// Column sums of exp(iw) over vocab rows. Block 0 also hosts one-time zero
// duties (out, colsum, flags) — consumers run in later kernels (stream order).
__global__ void k_colpart(const float* __restrict__ iw, float* __restrict__ psum,
                          float* __restrict__ out, float* __restrict__ colsum,
                          unsigned* __restrict__ flags) {
  const int blk = blockIdx.x;        // 250
  const int tid = threadIdx.x;       // 256
  if (blk == 0) {
    if (tid == 0) out[0] = 0.f;
    flags[tid] = 0u;                               // 256 flags (2 chains x 128)
    colsum[tid] = 0.f; colsum[tid + 256] = 0.f;
  }
  const int cg = tid & 127;          // float4 column group
  const int rh = tid >> 7;           // row half
  const int r0 = blk * 128 + rh * 64;
  const float4* iw4 = (const float4*)iw;   // [32000][128] float4
  float4 s = make_float4(0.f, 0.f, 0.f, 0.f);
  #pragma unroll 4
  for (int r = 0; r < 64; ++r) {
    float4 x = iw4[(size_t)(r0 + r) * 128 + cg];
    s.x += __expf(x.x); s.y += __expf(x.y); s.z += __expf(x.z); s.w += __expf(x.w);
  }
  ((float4*)psum)[(size_t)(blk * 2 + rh) * 128 + cg] = s;
}

// 25 blocks x 512 thr: block p sums partial rows [20p, 20p+20) -> atomicAdd.
__global__ void k_colreduce(const float* __restrict__ psum, float* __restrict__ colsum) {
  const int c = threadIdx.x;         // 512
  const int p0 = blockIdx.x * 20;
  float s = 0.f;
  #pragma unroll 5
  for (int p = 0; p < 20; ++p) s += psum[(size_t)(p0 + p) * SS + c];
  atomicAdd(&colsum[c], s);
}

// P[i][j] = softmax(transition[i,:])[j] (row-major), q0vec[i] = sum_j P[i,j]*sb[j].
// softmax(begin) recomputed locally per block (no separate k_begin kernel).
__global__ void k_transP(const float* __restrict__ trans, const float* __restrict__ begin,
                         float* __restrict__ P, float* __restrict__ q0vec) {
  const int i = blockIdx.x;     // 512 rows
  const int lane = threadIdx.x; // 64
  // local softmax(begin)
  float bx[8];
  float bm = -1e30f;
  #pragma unroll
  for (int cc = 0; cc < 8; ++cc) { bx[cc] = begin[cc * 64 + lane]; bm = fmaxf(bm, bx[cc]); }
  #pragma unroll
  for (int o = 32; o; o >>= 1) bm = fmaxf(bm, __shfl_xor(bm, o));
  float bs = 0.f;
  #pragma unroll
  for (int cc = 0; cc < 8; ++cc) { bx[cc] = __expf(bx[cc] - bm); bs += bx[cc]; }
  #pragma unroll
  for (int o = 32; o; o >>= 1) bs += __shfl_xor(bs, o);
  const float binv = 1.f / bs;

  const float* rp = trans + (size_t)i * SS;
  float xs[8];
  float m = -1e30f;
  #pragma unroll
  for (int cc = 0; cc < 8; ++cc) { xs[cc] = rp[cc * 64 + lane]; m = fmaxf(m, xs[cc]); }
  #pragma unroll
  for (int o = 32; o; o >>= 1) m = fmaxf(m, __shfl_xor(m, o));
  float s = 0.f;
  #pragma unroll
  for (int cc = 0; cc < 8; ++cc) s += __expf(xs[cc] - m);
  #pragma unroll
  for (int o = 32; o; o >>= 1) s += __shfl_xor(s, o);
  const float lse = m + __logf(s);
  float qa = 0.f;
  #pragma unroll
  for (int cc = 0; cc < 8; ++cc) {
    float p = __expf(xs[cc] - lse);
    P[(size_t)i * SS + cc * 64 + lane] = p;
    qa += p * (bx[cc] * binv);
  }
  #pragma unroll
  for (int o = 32; o; o >>= 1) qa += __shfl_xor(qa, o);
  if (lane == 0) q0vec[i] = qa;
}

// ---------------- persistent superstep kernel ----------------
// 256 blocks x 256 thr, cooperative. chain c = blk&1, col group g = blk>>1.
// Wave h = j-quarter. w ring WRITE-ONCE (slot = timestep): no stale-L2 hazard.
//
// Sync fabric = R3's proven shape (the ONLY one of 4 tested that doesn't
// degrade the fabric): single sleepy scout (wave 0, s_sleep(2)) polls the
// chain's 128 flags between two __syncthreads; all other waves parked at the
// barrier during the poll. R4/R5/R6 all showed that extra concurrent pollers
// (per-wave dataflow, hot scouts) add ~2.4 us/step of fabric contention.
//
// R7 delta vs R3: the poll SKIPS the own block's flag. Own w visibility is
// ordered by program order on wave 0 (w stores -> vmcnt(0) ack -> flag store
// -> poll -> release barrier -> w loads), so observing our own flag through
// L3 is a wasted round trip — and it's systematically the last to land.
__global__ __launch_bounds__(256) void k_persist(
    const float* __restrict__ P, const float* __restrict__ q0vec,
    const float* __restrict__ iw, const float* __restrict__ colsum,
    const int* __restrict__ sent, float* __restrict__ wring,
    float* __restrict__ dotpart, unsigned* __restrict__ flags) {
  const int c = blockIdx.x & 1;
  const int g = blockIdx.x >> 1;       // 0..127
  const int lane = threadIdx.x & 63;   // batch b
  const int h = __builtin_amdgcn_readfirstlane(threadIdx.x >> 6); // j-quarter
  const int i0 = g << 2;
  const int kmax = c ? 127 : 128;
  unsigned* const myflags = flags + (c << 7);      // [c][g]
  const bool ownA = (lane == g);                   // own flag in va set
  const bool ownB = (lane + 64 == g);              // own flag in vb set

  // colLSE computed locally
  float4 cl;
  cl.x = __logf(colsum[i0 + 0]); cl.y = __logf(colsum[i0 + 1]);
  cl.z = __logf(colsum[i0 + 2]); cl.w = __logf(colsum[i0 + 3]);

  const float4* const P0 = (const float4*)(P + (size_t)(i0 + 0) * SS) + h * 32;
  const float4* const P1 = (const float4*)(P + (size_t)(i0 + 1) * SS) + h * 32;
  const float4* const P2 = (const float4*)(P + (size_t)(i0 + 2) * SS) + h * 32;
  const float4* const P3 = (const float4*)(P + (size_t)(i0 + 3) * SS) + h * 32;

  __shared__ float4 red[4][64];

  for (int k = 0; k <= kmax; ++k) {
    const int t0 = 2 * k;
    const int tw = t0 + c;
    const int td = tw - 1;
    const bool doW = (h == 0) && (tw <= 254);
    const bool doD = (h == 1) && (td >= 0);

    // Issue the scattered iw gathers BEFORE the barrier/poll: their L2/L3
    // latency hides under the whole sync phase.
    float4 ivW = make_float4(0.f, 0.f, 0.f, 0.f);
    float4 ivD = make_float4(0.f, 0.f, 0.f, 0.f);
    if (doW) {
      const int row = sent[lane * TT + tw];
      ivW = *(const float4*)(iw + (size_t)row * SS + i0);
    }
    if (doD) {
      const int row = sent[lane * TT + td];
      ivD = *(const float4*)(iw + (size_t)row * SS + i0);
    }

    if (k > 0) {
      __syncthreads();  // previous iteration's red reads + epilogue complete
      if (h == 0) {
        const unsigned tgt = (unsigned)k;
        for (;;) {
          const unsigned va = __hip_atomic_load(myflags + lane, __ATOMIC_RELAXED,
                                                __HIP_MEMORY_SCOPE_AGENT);
          const unsigned vb = __hip_atomic_load(myflags + 64 + lane, __ATOMIC_RELAXED,
                                                __HIP_MEMORY_SCOPE_AGENT);
          const bool ok = ((va >= tgt) || ownA) && ((vb >= tgt) || ownB);
          if (__all(ok)) break;
          __builtin_amdgcn_s_sleep(2);
        }
      }
      __syncthreads();
    }

    float a0 = 0.f, a1 = 0.f, a2 = 0.f, a3 = 0.f;
    if (t0 == 0) {
      if (h == 0) {
        a0 = q0vec[i0 + 0]; a1 = q0vec[i0 + 1];
        a2 = q0vec[i0 + 2]; a3 = q0vec[i0 + 3];
      }
    } else {
      // Full-depth prefetch: all 32 w float4 loads in flight at once
      // (one L3 round-trip), then the FMA stream against L1/L2-resident P.
      const float4* wv = (const float4*)(wring + (size_t)(tw - 2) * WSLOT)
                         + (size_t)h * 32 * 64;
      float4 wr[32];
      #pragma unroll
      for (int u = 0; u < 32; ++u) wr[u] = wv[u * 64 + lane];
      #pragma unroll
      for (int u = 0; u < 32; ++u) {
        const float4 p0 = P0[u];
        const float4 p1 = P1[u];
        const float4 p2 = P2[u];
        const float4 p3 = P3[u];
        a0 += wr[u].x * p0.x + wr[u].y * p0.y + wr[u].z * p0.z + wr[u].w * p0.w;
        a1 += wr[u].x * p1.x + wr[u].y * p1.y + wr[u].z * p1.z + wr[u].w * p1.w;
        a2 += wr[u].x * p2.x + wr[u].y * p2.y + wr[u].z * p2.z + wr[u].w * p2.w;
        a3 += wr[u].x * p3.x + wr[u].y * p3.y + wr[u].z * p3.z + wr[u].w * p3.w;
      }
    }

    red[h][lane] = make_float4(a0, a1, a2, a3);
    __syncthreads();

    if (doW) {
      const float4 r0 = red[0][lane], r1 = red[1][lane];
      const float4 r2 = red[2][lane], r3 = red[3][lane];
      const float s0 = (r0.x + r1.x) + (r2.x + r3.x);
      const float s1 = (r0.y + r1.y) + (r2.y + r3.y);
      const float s2 = (r0.z + r1.z) + (r2.z + r3.z);
      const float s3 = (r0.w + r1.w) + (r2.w + r3.w);
      float w0 = s0 * __expf(ivW.x - cl.x);
      float w1 = s1 * __expf(ivW.y - cl.y);
      float w2 = s2 * __expf(ivW.z - cl.z);
      float w3 = s3 * __expf(ivW.w - cl.w);
      float c0 = w0, c1 = w1, c2 = w2, c3 = w3;
      #pragma unroll
      for (int o = 32; o; o >>= 1) {
        c0 += __shfl_xor(c0, o);
        c1 += __shfl_xor(c1, o);
        c2 += __shfl_xor(c2, o);
        c3 += __shfl_xor(c3, o);
      }
      // write-through (agent) stores: data reaches L3 (coherence point)
      union { float2 f; unsigned long long u; } lo, hi;
      lo.f = make_float2(w0 / c0, w1 / c1);
      hi.f = make_float2(w2 / c2, w3 / c3);
      unsigned long long* wd = (unsigned long long*)
          ((float4*)(wring + (size_t)tw * WSLOT) + (g * 64 + lane));
      __hip_atomic_store(wd, lo.u, __ATOMIC_RELAXED, __HIP_MEMORY_SCOPE_AGENT);
      __hip_atomic_store(wd + 1, hi.u, __ATOMIC_RELAXED, __HIP_MEMORY_SCOPE_AGENT);
      asm volatile("s_waitcnt vmcnt(0)" ::: "memory");  // w acked at L3
      if (lane == 0)
        __hip_atomic_store(&myflags[g], (unsigned)(k + 1), __ATOMIC_RELAXED,
                           __HIP_MEMORY_SCOPE_AGENT);
    } else if (doD) {
      const float4 r0 = red[0][lane], r1 = red[1][lane];
      const float4 r2 = red[2][lane], r3 = red[3][lane];
      const float s0 = (r0.x + r1.x) + (r2.x + r3.x);
      const float s1 = (r0.y + r1.y) + (r2.y + r3.y);
      const float s2 = (r0.z + r1.z) + (r2.z + r3.z);
      const float s3 = (r0.w + r1.w) + (r2.w + r3.w);
      const float dp = s0 * __expf(ivD.x - cl.x)
                     + s1 * __expf(ivD.y - cl.y)
                     + s2 * __expf(ivD.z - cl.z)
                     + s3 * __expf(ivD.w - cl.w);
      dotpart[((size_t)td * NS + g) * BB + lane] = dp;  // plain store: k_final is a
                                                        // separate kernel (boundary flush)
    }
  }
}

// ---------------- final reduction ----------------
__global__ void k_final(const float* __restrict__ dotpart, const float* __restrict__ masks,
                        float* __restrict__ out) {
  const int t = blockIdx.x;    // 256
  const int tid = threadIdx.x; // 256
  const int b = tid & 63, g = tid >> 6;
  float sum = 0.f;
  for (int s = g; s < NS; s += 4) sum += dotpart[((size_t)t * NS + s) * BB + b];
  __shared__ float red[4][64];
  red[g][b] = sum;
  __syncthreads();
  if (g == 0) {
    float tot = (red[0][b] + red[1][b]) + (red[2][b] + red[3][b]);
    float v = __logf(tot) * masks[b * TT + t];
    #pragma unroll
    for (int o = 32; o; o >>= 1) v += __shfl_xor(v, o);
    if (b == 0) atomicAdd(out, v);
  }
}

extern "C" void kernel_launch(void* const* d_in, const int* in_sizes, int n_in,
                              void* d_out, int out_size, void* d_ws, size_t ws_size,
                              hipStream_t stream) {
  const int* sent = (const int*)d_in[0];     // [64][256] int32
  const float* masks = (const float*)d_in[1];// [64][256]
  const float* iw = (const float*)d_in[2];   // [32000][512]
  const float* trans = (const float*)d_in[3];// [512][512]
  const float* begin = (const float*)d_in[4];// [512]
  float* out = (float*)d_out;
  float* ws = (float*)d_ws;

  // workspace carve (floats)
  float* P = ws;                            // 262144
  float* psum = P + 262144;                 // 500*512 = 256000
  float* colsum = psum + 256000;            // 512
  float* q0vec = colsum + 512;              // 512
  float* dotpart = q0vec + 512;             // 256*128*64 = 2097152
  unsigned* flags = (unsigned*)(dotpart + 2097152); // 256 used, 512 reserved
  float* wring = (float*)flags + 512;       // 255 * 32768 = 8355840 (~33.4 MB)
  // total ~44 MB

  k_colpart<<<250, 256, 0, stream>>>(iw, psum, out, colsum, flags);
  k_colreduce<<<25, 512, 0, stream>>>(psum, colsum);
  k_transP<<<512, 64, 0, stream>>>(trans, begin, P, q0vec);

  {
    const float* Pp = P;
    const float* q0p = q0vec;
    const float* iwp = iw;
    const float* csp = colsum;
    const int* sentp = sent;
    float* wrp = wring;
    float* dpp = dotpart;
    unsigned* fp = flags;
    void* args[] = {&Pp, &q0p, &iwp, &csp, &sentp, &wrp, &dpp, &fp};
    (void)hipLaunchCooperativeKernel((const void*)k_persist, dim3(256), dim3(256),
                                     args, 0, stream);
  }

  k_final<<<TT, 256, 0, stream>>>(dotpart, masks, out);
}